// Round 1
// baseline (794.955 us; speedup 1.0000x reference)
//
#include <hip/hip_runtime.h>

// Problem constants (fixed by the reference): B=16, M=1024, V=4.
// M is hard-coded for shift/mask index math; B and V are derived from in_sizes.
#define M_DIM 1024
#define M_SHIFT 10
#define BLOCK 256

__global__ void pose_loss_reduce(const float4* __restrict__ pred,
                                 const float4* __restrict__ gt,
                                 const int* __restrict__ Ms, int V,
                                 long long N, double* __restrict__ acc)
{
    // cumulative start offsets of each view (V <= 8 supported)
    int cum[9];
    cum[0] = 0;
#pragma unroll
    for (int v = 0; v < 8; ++v) {
        int m = (v < V) ? Ms[v] : 0;
        cum[v + 1] = cum[v] + m;
    }

    float tt = 0.f, ss = 0.f, it = 0.f, is = 0.f;

    long long stride = (long long)gridDim.x * blockDim.x;
    for (long long idx = (long long)blockIdx.x * blockDim.x + threadIdx.x;
         idx < N; idx += stride) {
        int j = (int)(idx & (M_DIM - 1));
        int i = (int)((idx >> M_SHIFT) & (M_DIM - 1));

        float4 p = pred[idx];
        float4 g = gt[idx];
        float d0 = p.x - g.x, d1 = p.y - g.y, d2 = p.z - g.z, d3 = p.w - g.w;
        float t = d0 * d0 + d1 * d1;
        float s = d2 * d2 + d3 * d3;

        int vi = 0, vj = 0;
#pragma unroll
        for (int v = 1; v < 8; ++v) {
            if (v < V) {
                vi += (i >= cum[v]);
                vj += (j >= cum[v]);
            }
        }
        tt += t;
        ss += s;
        if (vi != vj) { it += t; is += s; }
    }

    // 64-lane wave reduction
#pragma unroll
    for (int off = 32; off > 0; off >>= 1) {
        tt += __shfl_down(tt, off);
        ss += __shfl_down(ss, off);
        it += __shfl_down(it, off);
        is += __shfl_down(is, off);
    }

    __shared__ float l_tt[BLOCK / 64], l_ss[BLOCK / 64],
                     l_it[BLOCK / 64], l_is[BLOCK / 64];
    int wave = threadIdx.x >> 6;
    int lane = threadIdx.x & 63;
    if (lane == 0) {
        l_tt[wave] = tt; l_ss[wave] = ss;
        l_it[wave] = it; l_is[wave] = is;
    }
    __syncthreads();
    if (threadIdx.x == 0) {
        float a = 0.f, b = 0.f, c = 0.f, d = 0.f;
#pragma unroll
        for (int w = 0; w < BLOCK / 64; ++w) {
            a += l_tt[w]; b += l_ss[w]; c += l_it[w]; d += l_is[w];
        }
        atomicAdd(&acc[0], (double)a);
        atomicAdd(&acc[1], (double)b);
        atomicAdd(&acc[2], (double)c);
        atomicAdd(&acc[3], (double)d);
    }
}

__global__ void pose_loss_final(const double* __restrict__ acc,
                                const int* __restrict__ Ms, int V, int B,
                                float* __restrict__ out)
{
    double tt = acc[0], ss = acc[1], it = acc[2], is = acc[3];
    long long sumsq = 0;
    for (int v = 0; v < V; ++v) {
        long long m = Ms[v];
        sumsq += m * m;
    }
    double diag = (double)sumsq * (double)B;
    double offd = ((double)M_DIM * (double)M_DIM - (double)sumsq) * (double)B;

    double intra_t = tt - it;
    double intra_s = ss - is;

    double li_t = intra_t / diag;
    double le_t = it / offd;
    double li_s = intra_s / diag;
    double le_s = is / offd;

    const double A_T = 0.5, A_S = 0.75, A_TS = 0.5;
    double lt = A_T * le_t + (1.0 - A_T) * li_t;
    double ls = A_S * le_s + (1.0 - A_S) * li_s;
    double loss = A_TS * lt + (1.0 - A_TS) * ls;

    out[0] = (float)li_t;
    out[1] = (float)le_t;
    out[2] = (float)li_s;
    out[3] = (float)le_s;
    out[4] = (float)lt;
    out[5] = (float)ls;
    out[6] = (float)loss;
}

extern "C" void kernel_launch(void* const* d_in, const int* in_sizes, int n_in,
                              void* d_out, int out_size, void* d_ws, size_t ws_size,
                              hipStream_t stream)
{
    const float* pred = (const float*)d_in[0];
    const float* gt   = (const float*)d_in[1];
    const int*   Ms   = (const int*)d_in[2];
    int V = in_sizes[2];

    long long total = (long long)in_sizes[0];            // B*M*M*4
    long long N     = total / 4;                         // float4 groups
    int B           = (int)(total / (4LL * M_DIM * M_DIM));

    double* acc = (double*)d_ws;
    hipMemsetAsync(acc, 0, 4 * sizeof(double), stream);  // ws is poisoned 0xAA each call

    int grid = 8192;  // 2M threads, 8 float4-pairs each; plenty of waves/CU
    pose_loss_reduce<<<grid, BLOCK, 0, stream>>>(
        (const float4*)pred, (const float4*)gt, Ms, V, N, acc);
    pose_loss_final<<<1, 1, 0, stream>>>(acc, Ms, V, B, (float*)d_out);
}